// Round 5
// baseline (7493.549 us; speedup 1.0000x reference)
//
#include <hip/hip_runtime.h>
#include <math.h>

#define LSEQ 128
#define BATCH 64
#define EDIM 512
#define HDIM 1024
#define N3 3072
#define NWG 256
#define NTH 1024
#define GXT ((size_t)(N3 * BATCH))   // floats per time step in gxT ([3072][64])

// ---------------------------------------------------------------------------
// agent-scope (cross-XCD coherent) scalar load/store
// ---------------------------------------------------------------------------
__device__ __forceinline__ float sc1Ld(const float* p) {
    return __hip_atomic_load(p, __ATOMIC_RELAXED, __HIP_MEMORY_SCOPE_AGENT);
}
__device__ __forceinline__ void sc1St(float* p, float v) {
    __hip_atomic_store(p, v, __ATOMIC_RELAXED, __HIP_MEMORY_SCOPE_AGENT);
}

// Counter barrier (one fresh pre-zeroed counter per instance; monotone use).
__device__ __forceinline__ void cnt_bar(int* cnt) {
    __syncthreads();   // drains each wave's vmcnt before thread 0 arrives
    if (threadIdx.x == 0) {
        asm volatile("s_waitcnt vmcnt(0)" ::: "memory");
        __hip_atomic_fetch_add(cnt, 1, __ATOMIC_RELAXED, __HIP_MEMORY_SCOPE_AGENT);
        while (__hip_atomic_load(cnt, __ATOMIC_RELAXED, __HIP_MEMORY_SCOPE_AGENT) < NWG)
            __builtin_amdgcn_s_sleep(2);
    }
    __syncthreads();
}

// ---------------------------------------------------------------------------
// f32 tiled GEMM, optional row-gather on A. Output written BLOCK-TRANSPOSED:
//   C[(m>>6)][n][m&63]  (gxT layout [t][3072][64]), staged through LDS.
// ---------------------------------------------------------------------------
__global__ __launch_bounds__(256) void gemm_biasT(
    const float* __restrict__ A, const int* __restrict__ idx, int K,
    const float* __restrict__ Bm, const float* __restrict__ bias,
    float* __restrict__ C, int N)
{
    __shared__ float Sm[4352];          // As[32][68] @0, Bs[32][68] @2176
    float* As = Sm;
    float* Bs = Sm + 2176;
    const int tid = threadIdx.x;
    const int m0 = blockIdx.y * 64, n0 = blockIdx.x * 64;
    const int ty = tid >> 4, tx = tid & 15;

    float acc[4][4] = {};

    const int ra = tid >> 3;
    const int kq = (tid & 7) << 2;
    const int kb = tid >> 4;
    const int nq = (tid & 15) << 2;

    for (int k0 = 0; k0 < K; k0 += 32) {
        #pragma unroll
        for (int h2 = 0; h2 < 2; ++h2) {
            const int row = ra + h2 * 32;
            const int grow = idx ? idx[m0 + row] : (m0 + row);
            const float4 v = *reinterpret_cast<const float4*>(&A[(size_t)grow * K + k0 + kq]);
            As[(kq + 0) * 68 + row] = v.x; As[(kq + 1) * 68 + row] = v.y;
            As[(kq + 2) * 68 + row] = v.z; As[(kq + 3) * 68 + row] = v.w;
        }
        #pragma unroll
        for (int h2 = 0; h2 < 2; ++h2) {
            const int kk = kb + h2 * 16;
            *reinterpret_cast<float4*>(&Bs[kk * 68 + nq]) =
                *reinterpret_cast<const float4*>(&Bm[(size_t)(k0 + kk) * N + n0 + nq]);
        }
        __syncthreads();
        #pragma unroll
        for (int k = 0; k < 32; ++k) {
            const float4 a4 = *reinterpret_cast<const float4*>(&As[k * 68 + ty * 4]);
            const float4 b4 = *reinterpret_cast<const float4*>(&Bs[k * 68 + tx * 4]);
            const float av[4] = {a4.x, a4.y, a4.z, a4.w};
            const float bv[4] = {b4.x, b4.y, b4.z, b4.w};
            #pragma unroll
            for (int i = 0; i < 4; ++i)
                #pragma unroll
                for (int j = 0; j < 4; ++j)
                    acc[i][j] += av[i] * bv[j];
        }
        __syncthreads();
    }

    #pragma unroll
    for (int i = 0; i < 4; ++i) {
        float4 v = {acc[i][0] + bias[n0 + tx * 4 + 0],
                    acc[i][1] + bias[n0 + tx * 4 + 1],
                    acc[i][2] + bias[n0 + tx * 4 + 2],
                    acc[i][3] + bias[n0 + tx * 4 + 3]};
        *reinterpret_cast<float4*>(&Sm[(ty * 4 + i) * 65 + tx * 4]) = v;
    }
    __syncthreads();
    const int mloc = tid & 63, nq2 = tid >> 6;
    const size_t base = (size_t)blockIdx.y * ((size_t)N * 64) + (size_t)n0 * 64;
    #pragma unroll
    for (int q = 0; q < 16; ++q) {
        const int nl = nq2 * 16 + q;
        C[base + (size_t)nl * 64 + mloc] = Sm[mloc * 65 + nl];
    }
}

// ---------------------------------------------------------------------------
// GRU scan v5 — 1024 threads/WG (16 waves), WG owns 8 cols x 32 batches.
//   cg = wg>>1 (col group, c0 = cg*8), bg = wg&1 (batch group, b0 = bg*32).
// gxT layout [t][3072][64]; overlays into PREVIOUS consumed zone as before:
//   h(t)  -> zone(u)[c][b]        (sc1-written at B(t))
//   rh(t) -> zone(u)[1024+c][b]   (sc1-written at A(t))
//   zone(u) = gxT + u*GXT for 0<=u<L else scr (per-direction scratch).
// Gate regions are consumed only via sc1 (no cache allocation); overlay data
// is plain-read only at fresh addresses after a barrier.
// ---------------------------------------------------------------------------
__global__ __launch_bounds__(NTH) void gru_scan5(
    float* __restrict__ gxT,
    float* __restrict__ scr,
    const float* __restrict__ Whzr,   // [1024][2048]
    const float* __restrict__ bhzr,
    const float* __restrict__ Whh,    // [1024][1024]
    const float* __restrict__ bhh,
    const float* __restrict__ mask,   // [L][B]
    float* __restrict__ out,          // [L][B][1024]
    int* __restrict__ bar,            // [2*LSEQ] pre-zeroed
    int reverse)
{
    __shared__ float Wzr_l[HDIM * 16];   // [k][8z|8r]  64KB
    __shared__ float Whh_l[HDIM * 8];    // [k][8c]     32KB
    __shared__ float part[8192];         // 32KB reduce scratch
    __shared__ float zl[256];            // [c][32b]
    __shared__ float hold[256];          // [c][32b]

    const int wg = blockIdx.x, tid = threadIdx.x;
    const int w = tid >> 6, lane = tid & 63;
    const int bq = lane & 7, gp = lane >> 3;
    const int c0 = (wg >> 1) * 8;
    const int b0 = (wg & 1) * 32;

    // one-time weight staging (k = tid)
    {
        const int k = tid;
        *(float4*)&Wzr_l[k * 16]      = *(const float4*)&Whzr[(size_t)k * 2048 + c0];
        *(float4*)&Wzr_l[k * 16 + 4]  = *(const float4*)&Whzr[(size_t)k * 2048 + c0 + 4];
        *(float4*)&Wzr_l[k * 16 + 8]  = *(const float4*)&Whzr[(size_t)k * 2048 + 1024 + c0];
        *(float4*)&Wzr_l[k * 16 + 12] = *(const float4*)&Whzr[(size_t)k * 2048 + 1024 + c0 + 4];
        *(float4*)&Whh_l[k * 8]       = *(const float4*)&Whh[(size_t)k * 1024 + c0];
        *(float4*)&Whh_l[k * 8 + 4]   = *(const float4*)&Whh[(size_t)k * 1024 + c0 + 4];
    }

    // reduce-A mapping (tid < 512): output (gate gcA, batch bA)
    const int remA = tid & 255;
    const int lqA = remA >> 2, eA = remA & 3;
    const int bA  = (lqA & 7) * 4 + ((tid >> 8) & 1) * 2 + (eA >> 1);
    const int gcA = (lqA >> 3) * 2 + (eA & 1);
    const int colA = (gcA < 8) ? (c0 + gcA) : (1024 + c0 + gcA - 8);
    const float bzrA = bhzr[colA & 2047];
    const int jA = gcA - 8;
    // reduce-B mapping (tid < 256): output (col cB, batch bB)
    const int lqB = tid >> 2, eB = tid & 3;
    const int bB = (lqB & 7) * 4 + eB;
    const int cB = lqB >> 3;
    const float bhhB = (tid < 256) ? bhh[c0 + cB] : 0.f;

    __syncthreads();

    for (int s = 0; s < LSEQ; ++s) {
        const int t  = reverse ? (LSEQ - 1 - s) : s;
        const int u  = reverse ? (t + 1) : (t - 1);
        const int up = reverse ? (t + 2) : (t - 2);
        float* zoneU = (u >= 0 && u < LSEQ) ? (gxT + (size_t)u * GXT) : scr;
        const float* zoneP = (up >= 0 && up < LSEQ) ? (gxT + (size_t)up * GXT) : scr;

        // ---- prefetches (pure-input regions; safe pre-barrier) ----
        float gateA = 0.f;
        if (tid < 512)
            gateA = sc1Ld(&gxT[(size_t)t * GXT + (size_t)colA * 64 + b0 + bA]);
        float gxcB = 0.f, mkB = 0.f;
        if (tid < 256) {
            gxcB = gxT[(size_t)t * GXT + (size_t)(2048 + c0 + cB) * 64 + b0 + bB];
            mkB  = mask[t * BATCH + b0 + bB];
            hold[cB * 32 + bB] = (s > 0) ? zoneP[(size_t)(c0 + cB) * 64 + b0 + bB] : 0.f;
        }

        // ---- phase A GEMM: z,r partials; wave w owns K-slice [64w, 64w+64) ----
        float2 a00 = {0,0}, a01 = {0,0}, a10 = {0,0}, a11 = {0,0};
        if (s > 0) {
            const float* hb = zoneP + (size_t)(w * 64) * 64 + b0 + bq * 4;
            const float* wb = &Wzr_l[(w * 64) * 16 + gp * 2];
            #pragma unroll 8
            for (int kk = 0; kk < 64; ++kk) {
                const float4 h4 = *(const float4*)(hb + (size_t)kk * 64);
                const float2 w2 = *(const float2*)(wb + kk * 16);
                a00.x += h4.x * w2.x; a00.y += h4.y * w2.x;
                a01.x += h4.z * w2.x; a01.y += h4.w * w2.x;
                a10.x += h4.x * w2.y; a10.y += h4.y * w2.y;
                a11.x += h4.z * w2.y; a11.y += h4.w * w2.y;
            }
        }
        {
            const float4 p0 = {a00.x, a10.x, a00.y, a10.y};
            const float4 p1 = {a01.x, a11.x, a01.y, a11.y};
            *(float4*)&part[w * 512 + lane * 4]       = p0;
            *(float4*)&part[w * 512 + 256 + lane * 4] = p1;
        }
        __syncthreads();
        if (tid < 512) {
            float sum = 0.f;
            #pragma unroll
            for (int ww = 0; ww < 16; ++ww) sum += part[ww * 512 + tid];
            const float pre = sum + bzrA + gateA;
            const float sig = 1.f / (1.f + expf(-pre));
            if (gcA < 8) {
                zl[gcA * 32 + bA] = sig;
            } else {
                const float rh = sig * hold[jA * 32 + bA];
                sc1St(&zoneU[(size_t)colA * 64 + b0 + bA], rh);
            }
        }
        cnt_bar(&bar[2 * s]);

        // ---- phase B GEMM: candidate partials over rh ----
        float2 q01 = {0,0}, q23 = {0,0};
        if (s > 0) {
            const float* rb  = zoneU + (size_t)(1024 + w * 64) * 64 + b0 + bq * 4;
            const float* wb2 = &Whh_l[(w * 64) * 8 + gp];
            #pragma unroll 8
            for (int kk = 0; kk < 64; ++kk) {
                const float4 r4 = *(const float4*)(rb + (size_t)kk * 64);
                const float wv = wb2[kk * 8];
                q01.x += r4.x * wv; q01.y += r4.y * wv;
                q23.x += r4.z * wv; q23.y += r4.w * wv;
            }
        }
        {
            const float4 pv = {q01.x, q01.y, q23.x, q23.y};
            *(float4*)&part[w * 256 + lane * 4] = pv;
        }
        __syncthreads();
        if (tid < 256) {
            float sum = 0.f;
            #pragma unroll
            for (int ww = 0; ww < 16; ++ww) sum += part[ww * 256 + tid];
            const float pre = sum + bhhB + gxcB;
            const float hc = tanhf(pre);
            const float z  = zl[cB * 32 + bB];
            const float ho = hold[cB * 32 + bB];
            float hn = ho + z * (hc - ho);
            hn = ho + mkB * (hn - ho);
            out[((size_t)t * BATCH + b0 + bB) * HDIM + c0 + cB] = hn;
            sc1St(&zoneU[(size_t)(c0 + cB) * 64 + b0 + bB], hn);
        }
        cnt_bar(&bar[2 * s + 1]);
    }
}

// ---------------------------------------------------------------------------
extern "C" void kernel_launch(void* const* d_in, const int* in_sizes, int n_in,
                              void* d_out, int out_size, void* d_ws, size_t ws_size,
                              hipStream_t stream) {
    const int*   xs      = (const int*)  d_in[0];
    const float* xs_mask = (const float*)d_in[1];
    const float* emb     = (const float*)d_in[2];
    const float* fw_Wx   = (const float*)d_in[3];
    const float* fw_bx   = (const float*)d_in[4];
    const float* fw_Whzr = (const float*)d_in[5];
    const float* fw_bhzr = (const float*)d_in[6];
    const float* fw_Whh  = (const float*)d_in[7];
    const float* fw_bhh  = (const float*)d_in[8];
    const float* bw_Wx   = (const float*)d_in[9];
    const float* bw_bx   = (const float*)d_in[10];
    const float* bw_Whzr = (const float*)d_in[11];
    const float* bw_bhzr = (const float*)d_in[12];
    const float* bw_Whh  = (const float*)d_in[13];
    const float* bw_bhh  = (const float*)d_in[14];
    float* outp = (float*)d_out;

    char* wp = (char*)d_ws;
    float* gxbuf = (float*)wp; wp += (size_t)LSEQ * GXT * sizeof(float);   // 100.7 MB
    float* scrF  = (float*)wp; wp += GXT * sizeof(float);                  // 768 KB
    float* scrB  = (float*)wp; wp += GXT * sizeof(float);                  // 768 KB
    int* barF    = (int*)wp;   wp += 2 * LSEQ * sizeof(int);
    int* barB    = (int*)wp;   wp += 2 * LSEQ * sizeof(int);

    hipMemsetAsync(barF, 0, 4 * LSEQ * sizeof(int), stream);

    const dim3 gemm_grid(N3 / 64, (LSEQ * BATCH) / 64);
    const dim3 gemm_blk(256);

    // ---- forward: gxT = (emb[xs] @ fw_Wx + fw_bx)^T-per-step ; scan ----
    hipLaunchKernelGGL(gemm_biasT, gemm_grid, gemm_blk, 0, stream,
                       emb, xs, EDIM, fw_Wx, fw_bx, gxbuf, N3);
    {
        int rev = 0;
        void* args[] = {(void*)&gxbuf, (void*)&scrF, (void*)&fw_Whzr, (void*)&fw_bhzr,
                        (void*)&fw_Whh, (void*)&fw_bhh, (void*)&xs_mask,
                        (void*)&outp, (void*)&barF, (void*)&rev};
        hipLaunchCooperativeKernel((const void*)gru_scan5, dim3(NWG), dim3(NTH),
                                   args, 0, stream);
    }

    // ---- backward: gxT = (right @ bw_Wx + bw_bx)^T-per-step ; scan ----
    {
        const float* rightp = (const float*)d_out;
        const int* noidx = nullptr;
        hipLaunchKernelGGL(gemm_biasT, gemm_grid, gemm_blk, 0, stream,
                           rightp, noidx, HDIM, bw_Wx, bw_bx, gxbuf, N3);
    }
    {
        int rev = 1;
        void* args[] = {(void*)&gxbuf, (void*)&scrB, (void*)&bw_Whzr, (void*)&bw_bhzr,
                        (void*)&bw_Whh, (void*)&bw_bhh, (void*)&xs_mask,
                        (void*)&outp, (void*)&barB, (void*)&rev};
        hipLaunchCooperativeKernel((const void*)gru_scan5, dim3(NWG), dim3(NTH),
                                   args, 0, stream);
    }
}

// Round 6
// 7366.776 us; speedup vs baseline: 1.0172x; 1.0172x over previous
//
#include <hip/hip_runtime.h>
#include <math.h>

#define LSEQ 128
#define BATCH 64
#define EDIM 512
#define HDIM 1024
#define N3 3072
#define NWG 256
#define NTH 1024
#define GXT ((size_t)(N3 * BATCH))   // floats per time step in gxT ([3072][64])

// ---------------------------------------------------------------------------
// agent-scope (cross-XCD coherent) scalar load/store
// ---------------------------------------------------------------------------
__device__ __forceinline__ float sc1Ld(const float* p) {
    return __hip_atomic_load(p, __ATOMIC_RELAXED, __HIP_MEMORY_SCOPE_AGENT);
}
__device__ __forceinline__ void sc1St(float* p, float v) {
    __hip_atomic_store(p, v, __ATOMIC_RELAXED, __HIP_MEMORY_SCOPE_AGENT);
}

// ---------------------------------------------------------------------------
// Group barrier over 128 WGs (one batch-group), tree arrival + release flags.
// base points at this instance's 16 pre-zeroed ints:
//   [0..3] mid counters (32 arrivals each) [4] root [8..11] release flags
// sub = member>>5 (0..3). Chain: vmcnt(0) -> add mid (RMWs serialize at IF,
// so the 32nd adder's view includes all 31 prior WGs' drained stores) -> last
// adds root -> root completer stores 4 release flags -> 32 pollers per flag.
// Every instance is fresh (monotone use), so flag==0 -> not released yet.
// ---------------------------------------------------------------------------
__device__ __forceinline__ void grp_bar(int* base, int sub) {
    __syncthreads();   // all 16 waves' loads consumed, stores issued
    if (threadIdx.x == 0) {
        asm volatile("s_waitcnt vmcnt(0)" ::: "memory");
        const int old = __hip_atomic_fetch_add(&base[sub], 1,
                            __ATOMIC_RELAXED, __HIP_MEMORY_SCOPE_AGENT);
        if (old == 31) {
            const int rold = __hip_atomic_fetch_add(&base[4], 1,
                                __ATOMIC_RELAXED, __HIP_MEMORY_SCOPE_AGENT);
            if (rold == 3) {
                #pragma unroll
                for (int r = 0; r < 4; ++r)
                    __hip_atomic_store(&base[8 + r], 1,
                        __ATOMIC_RELAXED, __HIP_MEMORY_SCOPE_AGENT);
            }
        }
        while (__hip_atomic_load(&base[8 + sub],
                   __ATOMIC_RELAXED, __HIP_MEMORY_SCOPE_AGENT) == 0)
            __builtin_amdgcn_s_sleep(2);
    }
    __syncthreads();
}

// ---------------------------------------------------------------------------
// f32 tiled GEMM, optional row-gather on A. Output written BLOCK-TRANSPOSED:
//   C[(m>>6)][n][m&63]  (gxT layout [t][3072][64]), staged through LDS.
// ---------------------------------------------------------------------------
__global__ __launch_bounds__(256) void gemm_biasT(
    const float* __restrict__ A, const int* __restrict__ idx, int K,
    const float* __restrict__ Bm, const float* __restrict__ bias,
    float* __restrict__ C, int N)
{
    __shared__ float Sm[4352];          // As[32][68] @0, Bs[32][68] @2176
    float* As = Sm;
    float* Bs = Sm + 2176;
    const int tid = threadIdx.x;
    const int m0 = blockIdx.y * 64, n0 = blockIdx.x * 64;
    const int ty = tid >> 4, tx = tid & 15;

    float acc[4][4] = {};

    const int ra = tid >> 3;
    const int kq = (tid & 7) << 2;
    const int kb = tid >> 4;
    const int nq = (tid & 15) << 2;

    for (int k0 = 0; k0 < K; k0 += 32) {
        #pragma unroll
        for (int h2 = 0; h2 < 2; ++h2) {
            const int row = ra + h2 * 32;
            const int grow = idx ? idx[m0 + row] : (m0 + row);
            const float4 v = *reinterpret_cast<const float4*>(&A[(size_t)grow * K + k0 + kq]);
            As[(kq + 0) * 68 + row] = v.x; As[(kq + 1) * 68 + row] = v.y;
            As[(kq + 2) * 68 + row] = v.z; As[(kq + 3) * 68 + row] = v.w;
        }
        #pragma unroll
        for (int h2 = 0; h2 < 2; ++h2) {
            const int kk = kb + h2 * 16;
            *reinterpret_cast<float4*>(&Bs[kk * 68 + nq]) =
                *reinterpret_cast<const float4*>(&Bm[(size_t)(k0 + kk) * N + n0 + nq]);
        }
        __syncthreads();
        #pragma unroll
        for (int k = 0; k < 32; ++k) {
            const float4 a4 = *reinterpret_cast<const float4*>(&As[k * 68 + ty * 4]);
            const float4 b4 = *reinterpret_cast<const float4*>(&Bs[k * 68 + tx * 4]);
            const float av[4] = {a4.x, a4.y, a4.z, a4.w};
            const float bv[4] = {b4.x, b4.y, b4.z, b4.w};
            #pragma unroll
            for (int i = 0; i < 4; ++i)
                #pragma unroll
                for (int j = 0; j < 4; ++j)
                    acc[i][j] += av[i] * bv[j];
        }
        __syncthreads();
    }

    #pragma unroll
    for (int i = 0; i < 4; ++i) {
        float4 v = {acc[i][0] + bias[n0 + tx * 4 + 0],
                    acc[i][1] + bias[n0 + tx * 4 + 1],
                    acc[i][2] + bias[n0 + tx * 4 + 2],
                    acc[i][3] + bias[n0 + tx * 4 + 3]};
        *reinterpret_cast<float4*>(&Sm[(ty * 4 + i) * 65 + tx * 4]) = v;
    }
    __syncthreads();
    const int mloc = tid & 63, nq2 = tid >> 6;
    const size_t base = (size_t)blockIdx.y * ((size_t)N * 64) + (size_t)n0 * 64;
    #pragma unroll
    for (int q = 0; q < 16; ++q) {
        const int nl = nq2 * 16 + q;
        C[base + (size_t)nl * 64 + mloc] = Sm[mloc * 65 + nl];
    }
}

// ---------------------------------------------------------------------------
// GRU scan v6 — v5 compute, group-split tree barriers.
// WG wg: batch group grp = wg&1 (b0 = grp*32), col owner c0 = (wg>>1)*8.
// Groups never exchange data (all h/rh/out slices are batch-local), so each
// group syncs independently among its 128 WGs.
// gxT layout [t][3072][64]; overlays into PREVIOUS consumed zone:
//   h(t)  -> zone(u)[c][b]        (sc1-written at B(t))
//   rh(t) -> zone(u)[1024+c][b]   (sc1-written at A(t))
//   zone(u) = gxT + u*GXT for 0<=u<L else scr (per-direction scratch).
// Gate regions are consumed only via sc1 (no cache allocation); overlay data
// is plain-read only at fresh addresses after a barrier.
// ---------------------------------------------------------------------------
__global__ __launch_bounds__(NTH) void gru_scan6(
    float* __restrict__ gxT,
    float* __restrict__ scr,
    const float* __restrict__ Whzr,   // [1024][2048]
    const float* __restrict__ bhzr,
    const float* __restrict__ Whh,    // [1024][1024]
    const float* __restrict__ bhh,
    const float* __restrict__ mask,   // [L][B]
    float* __restrict__ out,          // [L][B][1024]
    int* __restrict__ bar,            // [2*LSEQ*2][16] pre-zeroed
    int reverse)
{
    __shared__ float Wzr_l[HDIM * 16];   // [k][8z|8r]  64KB
    __shared__ float Whh_l[HDIM * 8];    // [k][8c]     32KB
    __shared__ float part[8192];         // 32KB reduce scratch
    __shared__ float zl[256];            // [c][32b]
    __shared__ float hold[256];          // [c][32b]

    const int wg = blockIdx.x, tid = threadIdx.x;
    const int w = tid >> 6, lane = tid & 63;
    const int bq = lane & 7, gp = lane >> 3;
    const int c0 = (wg >> 1) * 8;
    const int grp = wg & 1;
    const int b0 = grp * 32;
    const int sub = (wg >> 1) >> 5;      // member index >>5 : 0..3

    // one-time weight staging (k = tid)
    {
        const int k = tid;
        *(float4*)&Wzr_l[k * 16]      = *(const float4*)&Whzr[(size_t)k * 2048 + c0];
        *(float4*)&Wzr_l[k * 16 + 4]  = *(const float4*)&Whzr[(size_t)k * 2048 + c0 + 4];
        *(float4*)&Wzr_l[k * 16 + 8]  = *(const float4*)&Whzr[(size_t)k * 2048 + 1024 + c0];
        *(float4*)&Wzr_l[k * 16 + 12] = *(const float4*)&Whzr[(size_t)k * 2048 + 1024 + c0 + 4];
        *(float4*)&Whh_l[k * 8]       = *(const float4*)&Whh[(size_t)k * 1024 + c0];
        *(float4*)&Whh_l[k * 8 + 4]   = *(const float4*)&Whh[(size_t)k * 1024 + c0 + 4];
    }

    // reduce-A mapping (tid < 512): output (gate gcA, batch bA)
    const int remA = tid & 255;
    const int lqA = remA >> 2, eA = remA & 3;
    const int bA  = (lqA & 7) * 4 + ((tid >> 8) & 1) * 2 + (eA >> 1);
    const int gcA = (lqA >> 3) * 2 + (eA & 1);
    const int colA = (gcA < 8) ? (c0 + gcA) : (1024 + c0 + gcA - 8);
    const float bzrA = bhzr[colA & 2047];
    const int jA = gcA - 8;
    // reduce-B mapping (tid < 256): output (col cB, batch bB)
    const int lqB = tid >> 2, eB = tid & 3;
    const int bB = (lqB & 7) * 4 + eB;
    const int cB = lqB >> 3;
    const float bhhB = (tid < 256) ? bhh[c0 + cB] : 0.f;

    __syncthreads();

    for (int s = 0; s < LSEQ; ++s) {
        const int t  = reverse ? (LSEQ - 1 - s) : s;
        const int u  = reverse ? (t + 1) : (t - 1);
        const int up = reverse ? (t + 2) : (t - 2);
        float* zoneU = (u >= 0 && u < LSEQ) ? (gxT + (size_t)u * GXT) : scr;
        const float* zoneP = (up >= 0 && up < LSEQ) ? (gxT + (size_t)up * GXT) : scr;
        int* barA = bar + ((2 * s)     * 2 + grp) * 16;
        int* barB = bar + ((2 * s + 1) * 2 + grp) * 16;

        // ---- prefetches (pure-input regions; safe pre-barrier) ----
        float gateA = 0.f;
        if (tid < 512)
            gateA = sc1Ld(&gxT[(size_t)t * GXT + (size_t)colA * 64 + b0 + bA]);
        float gxcB = 0.f, mkB = 0.f;
        if (tid < 256) {
            gxcB = gxT[(size_t)t * GXT + (size_t)(2048 + c0 + cB) * 64 + b0 + bB];
            mkB  = mask[t * BATCH + b0 + bB];
            hold[cB * 32 + bB] = (s > 0) ? zoneP[(size_t)(c0 + cB) * 64 + b0 + bB] : 0.f;
        }

        // ---- phase A GEMM: z,r partials; wave w owns K-slice [64w, 64w+64) ----
        float2 a00 = {0,0}, a01 = {0,0}, a10 = {0,0}, a11 = {0,0};
        if (s > 0) {
            const float* hb = zoneP + (size_t)(w * 64) * 64 + b0 + bq * 4;
            const float* wb = &Wzr_l[(w * 64) * 16 + gp * 2];
            #pragma unroll 8
            for (int kk = 0; kk < 64; ++kk) {
                const float4 h4 = *(const float4*)(hb + (size_t)kk * 64);
                const float2 w2 = *(const float2*)(wb + kk * 16);
                a00.x += h4.x * w2.x; a00.y += h4.y * w2.x;
                a01.x += h4.z * w2.x; a01.y += h4.w * w2.x;
                a10.x += h4.x * w2.y; a10.y += h4.y * w2.y;
                a11.x += h4.z * w2.y; a11.y += h4.w * w2.y;
            }
        }
        {
            const float4 p0 = {a00.x, a10.x, a00.y, a10.y};
            const float4 p1 = {a01.x, a11.x, a01.y, a11.y};
            *(float4*)&part[w * 512 + lane * 4]       = p0;
            *(float4*)&part[w * 512 + 256 + lane * 4] = p1;
        }
        __syncthreads();
        if (tid < 512) {
            float sum = 0.f;
            #pragma unroll
            for (int ww = 0; ww < 16; ++ww) sum += part[ww * 512 + tid];
            const float pre = sum + bzrA + gateA;
            const float sig = 1.f / (1.f + expf(-pre));
            if (gcA < 8) {
                zl[gcA * 32 + bA] = sig;
            } else {
                const float rh = sig * hold[jA * 32 + bA];
                sc1St(&zoneU[(size_t)colA * 64 + b0 + bA], rh);
            }
        }
        grp_bar(barA, sub);

        // ---- phase B GEMM: candidate partials over rh ----
        float2 q01 = {0,0}, q23 = {0,0};
        if (s > 0) {
            const float* rb  = zoneU + (size_t)(1024 + w * 64) * 64 + b0 + bq * 4;
            const float* wb2 = &Whh_l[(w * 64) * 8 + gp];
            #pragma unroll 8
            for (int kk = 0; kk < 64; ++kk) {
                const float4 r4 = *(const float4*)(rb + (size_t)kk * 64);
                const float wv = wb2[kk * 8];
                q01.x += r4.x * wv; q01.y += r4.y * wv;
                q23.x += r4.z * wv; q23.y += r4.w * wv;
            }
        }
        {
            const float4 pv = {q01.x, q01.y, q23.x, q23.y};
            *(float4*)&part[w * 256 + lane * 4] = pv;
        }
        __syncthreads();
        if (tid < 256) {
            float sum = 0.f;
            #pragma unroll
            for (int ww = 0; ww < 16; ++ww) sum += part[ww * 256 + tid];
            const float pre = sum + bhhB + gxcB;
            const float hc = tanhf(pre);
            const float z  = zl[cB * 32 + bB];
            const float ho = hold[cB * 32 + bB];
            float hn = ho + z * (hc - ho);
            hn = ho + mkB * (hn - ho);
            out[((size_t)t * BATCH + b0 + bB) * HDIM + c0 + cB] = hn;
            sc1St(&zoneU[(size_t)(c0 + cB) * 64 + b0 + bB], hn);
        }
        grp_bar(barB, sub);
    }
}

// ---------------------------------------------------------------------------
extern "C" void kernel_launch(void* const* d_in, const int* in_sizes, int n_in,
                              void* d_out, int out_size, void* d_ws, size_t ws_size,
                              hipStream_t stream) {
    const int*   xs      = (const int*)  d_in[0];
    const float* xs_mask = (const float*)d_in[1];
    const float* emb     = (const float*)d_in[2];
    const float* fw_Wx   = (const float*)d_in[3];
    const float* fw_bx   = (const float*)d_in[4];
    const float* fw_Whzr = (const float*)d_in[5];
    const float* fw_bhzr = (const float*)d_in[6];
    const float* fw_Whh  = (const float*)d_in[7];
    const float* fw_bhh  = (const float*)d_in[8];
    const float* bw_Wx   = (const float*)d_in[9];
    const float* bw_bx   = (const float*)d_in[10];
    const float* bw_Whzr = (const float*)d_in[11];
    const float* bw_bhzr = (const float*)d_in[12];
    const float* bw_Whh  = (const float*)d_in[13];
    const float* bw_bhh  = (const float*)d_in[14];
    float* outp = (float*)d_out;

    // bar: per direction, [2*LSEQ phases][2 groups][16 ints] = 32KB
    const size_t BARN = (size_t)(2 * LSEQ) * 2 * 16;

    char* wp = (char*)d_ws;
    float* gxbuf = (float*)wp; wp += (size_t)LSEQ * GXT * sizeof(float);   // 100.7 MB
    float* scrF  = (float*)wp; wp += GXT * sizeof(float);                  // 768 KB
    float* scrB  = (float*)wp; wp += GXT * sizeof(float);                  // 768 KB
    int* barF    = (int*)wp;   wp += BARN * sizeof(int);
    int* barB    = (int*)wp;   wp += BARN * sizeof(int);

    hipMemsetAsync(barF, 0, 2 * BARN * sizeof(int), stream);

    const dim3 gemm_grid(N3 / 64, (LSEQ * BATCH) / 64);
    const dim3 gemm_blk(256);

    // ---- forward: gxT = (emb[xs] @ fw_Wx + fw_bx)^T-per-step ; scan ----
    hipLaunchKernelGGL(gemm_biasT, gemm_grid, gemm_blk, 0, stream,
                       emb, xs, EDIM, fw_Wx, fw_bx, gxbuf, N3);
    {
        int rev = 0;
        void* args[] = {(void*)&gxbuf, (void*)&scrF, (void*)&fw_Whzr, (void*)&fw_bhzr,
                        (void*)&fw_Whh, (void*)&fw_bhh, (void*)&xs_mask,
                        (void*)&outp, (void*)&barF, (void*)&rev};
        hipLaunchCooperativeKernel((const void*)gru_scan6, dim3(NWG), dim3(NTH),
                                   args, 0, stream);
    }

    // ---- backward: gxT = (right @ bw_Wx + bw_bx)^T-per-step ; scan ----
    {
        const float* rightp = (const float*)d_out;
        const int* noidx = nullptr;
        hipLaunchKernelGGL(gemm_biasT, gemm_grid, gemm_blk, 0, stream,
                           rightp, noidx, HDIM, bw_Wx, bw_bx, gxbuf, N3);
    }
    {
        int rev = 1;
        void* args[] = {(void*)&gxbuf, (void*)&scrB, (void*)&bw_Whzr, (void*)&bw_bhzr,
                        (void*)&bw_Whh, (void*)&bw_bhh, (void*)&xs_mask,
                        (void*)&outp, (void*)&barB, (void*)&rev};
        hipLaunchCooperativeKernel((const void*)gru_scan6, dim3(NWG), dim3(NTH),
                                   args, 0, stream);
    }
}